// Round 8
// baseline (243.214 us; speedup 1.0000x reference)
//
#include <hip/hip_runtime.h>
#include <math.h>

#define Bc 4
#define Tc 512
#define Fc 512
#define Dc 256
#define RPB 8  // rows per block in projection kernel
#define PF 2   // scan prefetch depth (register circular buffer)

typedef float floatx4 __attribute__((ext_vector_type(4)));

__device__ __forceinline__ float wred(float v) {
#pragma unroll
  for (int off = 32; off; off >>= 1) v += __shfl_xor(v, off, 64);
  return v;
}

// Quad wave64 sum-reduce via DPP, 4 values interleaved so the 6 dependent
// rounds pipeline across independent values.
__device__ __forceinline__ void wred4_dpp(float& a, float& c, float& e,
                                          float& g) {
#define DPP_STEP(ctrl, rmask)                                                 \
  {                                                                           \
    float ta = __int_as_float(__builtin_amdgcn_update_dpp(                    \
        0, __float_as_int(a), (ctrl), (rmask), 0xf, true));                   \
    float tc = __int_as_float(__builtin_amdgcn_update_dpp(                    \
        0, __float_as_int(c), (ctrl), (rmask), 0xf, true));                   \
    float te = __int_as_float(__builtin_amdgcn_update_dpp(                    \
        0, __float_as_int(e), (ctrl), (rmask), 0xf, true));                   \
    float tg = __int_as_float(__builtin_amdgcn_update_dpp(                    \
        0, __float_as_int(g), (ctrl), (rmask), 0xf, true));                   \
    a += ta;                                                                  \
    c += tc;                                                                  \
    e += te;                                                                  \
    g += tg;                                                                  \
  }
  DPP_STEP(0x111, 0xf)  // row_shr:1
  DPP_STEP(0x112, 0xf)  // row_shr:2
  DPP_STEP(0x114, 0xf)  // row_shr:4
  DPP_STEP(0x118, 0xf)  // row_shr:8
  DPP_STEP(0x142, 0xa)  // row_bcast:15 -> rows 1,3
  DPP_STEP(0x143, 0xc)  // row_bcast:31 -> rows 2,3
#undef DPP_STEP
  a = __int_as_float(__builtin_amdgcn_readlane(__float_as_int(a), 63));
  c = __int_as_float(__builtin_amdgcn_readlane(__float_as_int(c), 63));
  e = __int_as_float(__builtin_amdgcn_readlane(__float_as_int(e), 63));
  g = __int_as_float(__builtin_amdgcn_readlane(__float_as_int(g), 63));
}

// ---------------------------------------------------------------------------
// Kernel 1: LayerNorm + K/Q/V/beta/shortcut projections + sum-normalize + kq
// Weight loads software-pipelined one 4-f tile ahead (A/B register tiles):
// 128 FMAs (~256cy) per tile cover the ~200cy L2 load latency exposed at
// 1 wave/SIMD.
// ---------------------------------------------------------------------------
__global__ __launch_bounds__(256) void proj_kernel(
    const float* __restrict__ x, const float* __restrict__ Wk,
    const float* __restrict__ Wq, const float* __restrict__ Wv,
    const float* __restrict__ Wb, const float* __restrict__ gamma,
    const float* __restrict__ beta_ln, const float* __restrict__ Wsc,
    const float* __restrict__ bsc, float* __restrict__ Ko,
    float* __restrict__ Qo, float* __restrict__ Vo, float* __restrict__ ysco,
    float* __restrict__ betao, float* __restrict__ kqo) {
  __shared__ __align__(16) float xn[RPB][Fc];
  __shared__ float red[4][32];
  __shared__ float fin[32];

  const int tid = threadIdx.x;
  const int wave = tid >> 6, lane = tid & 63;
  const int row0 = blockIdx.x * RPB;

#pragma unroll
  for (int rr = 0; rr < 2; ++rr) {
    const int r = wave * 2 + rr;
    const float* xr = x + (size_t)(row0 + r) * Fc;
    float4 a = *(const float4*)&xr[lane * 8];
    float4 b = *(const float4*)&xr[lane * 8 + 4];
    float s8 = a.x + a.y + a.z + a.w + b.x + b.y + b.z + b.w;
    float mu = wred(s8) * (1.0f / Fc);
    float d0 = a.x - mu, d1 = a.y - mu, d2 = a.z - mu, d3 = a.w - mu;
    float d4 = b.x - mu, d5 = b.y - mu, d6 = b.z - mu, d7 = b.w - mu;
    float sq = d0 * d0 + d1 * d1 + d2 * d2 + d3 * d3 + d4 * d4 + d5 * d5 +
               d6 * d6 + d7 * d7;
    float var = wred(sq) * (1.0f / Fc);
    float rs = rsqrtf(var + 1e-5f);
    float4 g0 = *(const float4*)&gamma[lane * 8];
    float4 g1 = *(const float4*)&gamma[lane * 8 + 4];
    float4 bl0 = *(const float4*)&beta_ln[lane * 8];
    float4 bl1 = *(const float4*)&beta_ln[lane * 8 + 4];
    float4 o0 = make_float4(d0 * rs * g0.x + bl0.x, d1 * rs * g0.y + bl0.y,
                            d2 * rs * g0.z + bl0.z, d3 * rs * g0.w + bl0.w);
    float4 o1 = make_float4(d4 * rs * g1.x + bl1.x, d5 * rs * g1.y + bl1.y,
                            d6 * rs * g1.z + bl1.z, d7 * rs * g1.w + bl1.w);
    *(float4*)&xn[r][lane * 8] = o0;
    *(float4*)&xn[r][lane * 8 + 4] = o1;
  }
  __syncthreads();

  const int d = tid;
  float accK[RPB], accQ[RPB], accV[RPB], accS[RPB];
#pragma unroll
  for (int r = 0; r < RPB; ++r) accK[r] = accQ[r] = accV[r] = accS[r] = 0.0f;

  float wkA[4], wqA[4], wvA[4], wsA[4];
  float wkB[4], wqB[4], wvB[4], wsB[4];

#define LOADW(buf, fbase)                                                     \
  {                                                                           \
    _Pragma("unroll") for (int ff = 0; ff < 4; ++ff) {                        \
      wk##buf[ff] = Wk[(size_t)((fbase) + ff) * Dc + d];                      \
      wq##buf[ff] = Wq[(size_t)((fbase) + ff) * Dc + d];                      \
      wv##buf[ff] = Wv[(size_t)((fbase) + ff) * Dc + d];                      \
      ws##buf[ff] = Wsc[(size_t)((fbase) + ff) * Dc + d];                     \
    }                                                                         \
  }
#define COMPW(buf, fbase)                                                     \
  {                                                                           \
    _Pragma("unroll") for (int r = 0; r < RPB; ++r) {                         \
      float4 xr = *(const float4*)&xn[r][(fbase)];                            \
      accK[r] = fmaf(xr.w, wk##buf[3],                                        \
                     fmaf(xr.z, wk##buf[2],                                   \
                          fmaf(xr.y, wk##buf[1],                              \
                               fmaf(xr.x, wk##buf[0], accK[r]))));            \
      accQ[r] = fmaf(xr.w, wq##buf[3],                                        \
                     fmaf(xr.z, wq##buf[2],                                   \
                          fmaf(xr.y, wq##buf[1],                              \
                               fmaf(xr.x, wq##buf[0], accQ[r]))));            \
      accV[r] = fmaf(xr.w, wv##buf[3],                                        \
                     fmaf(xr.z, wv##buf[2],                                   \
                          fmaf(xr.y, wv##buf[1],                              \
                               fmaf(xr.x, wv##buf[0], accV[r]))));            \
      accS[r] = fmaf(xr.w, ws##buf[3],                                        \
                     fmaf(xr.z, ws##buf[2],                                   \
                          fmaf(xr.y, ws##buf[1],                              \
                               fmaf(xr.x, ws##buf[0], accS[r]))));            \
    }                                                                         \
  }

  LOADW(A, 0)
  for (int f = 0; f < Fc; f += 8) {
    LOADW(B, f + 4)
    COMPW(A, f)
    const int fn = (f + 8 < Fc) ? f + 8 : f;  // clamped dummy on last iter
    LOADW(A, fn)
    COMPW(B, f + 4)
  }
#undef LOADW
#undef COMPW

  float pk[RPB], pq[RPB];
#pragma unroll
  for (int r = 0; r < RPB; ++r) {
    pk[r] = fmaxf(accK[r], 0.0f);
    pq[r] = fmaxf(accQ[r], 0.0f);
  }
#pragma unroll
  for (int r = 0; r < RPB; ++r) {
    float p0 = wred(pk[r]);
    float p1 = wred(pq[r]);
    float p2 = wred(pk[r] * pq[r]);
    float pb = xn[r][tid] * Wb[tid] + xn[r][tid + 256] * Wb[tid + 256];
    float p3 = wred(pb);
    if (lane == 0) {
      red[wave][r * 4 + 0] = p0;
      red[wave][r * 4 + 1] = p1;
      red[wave][r * 4 + 2] = p2;
      red[wave][r * 4 + 3] = p3;
    }
  }
  __syncthreads();
  if (tid < 32) fin[tid] = red[0][tid] + red[1][tid] + red[2][tid] + red[3][tid];
  __syncthreads();

#pragma unroll
  for (int r = 0; r < RPB; ++r) {
    size_t row = (size_t)(row0 + r);
    float invK = 1.0f / (1e-5f + fin[r * 4 + 0]);
    float invQ = 1.0f / (1e-5f + fin[r * 4 + 1]);
    Ko[row * Dc + d] = pk[r] * invK;
    Qo[row * Dc + d] = pq[r] * invQ;
    Vo[row * Dc + d] = accV[r];
    ysco[row * Dc + d] = accS[r] + bsc[d];
  }
  if (tid < RPB) {
    size_t row = (size_t)(row0 + tid);
    float invK = 1.0f / (1e-5f + fin[tid * 4 + 0]);
    float invQ = 1.0f / (1e-5f + fin[tid * 4 + 1]);
    betao[row] = 1.0f / (1.0f + expf(-fin[tid * 4 + 3]));
    kqo[row] = fin[tid * 4 + 2] * invK * invQ;
  }
}

// ---------------------------------------------------------------------------
// Kernel 2: row-parallel state scan, TWO chains per wave (rows i0, i0+1).
// Intra-wave ILP: while chain-0's DPP reduce drains, chain-1's independent
// instructions issue. k/q are shared between the chains (same (b,t)) ->
// half the k/q load traffic. 256 blocks x 128 threads, XCD swizzle (each
// XCD serves one batch -> 2 MB read set in its 4 MB L2), nt stores keep
// the 512 MB states stream out of L2.
// ---------------------------------------------------------------------------
__global__ __launch_bounds__(128) void scan_kernel(
    const float* __restrict__ S0, const float* __restrict__ K,
    const float* __restrict__ Q, const float* __restrict__ V,
    const float* __restrict__ ysc, const float* __restrict__ beta,
    const float* __restrict__ kq, float* __restrict__ yout,
    float* __restrict__ states) {
  const int tid = threadIdx.x;
  const int wave = tid >> 6, lane = tid & 63;
  const int bid = blockIdx.x;               // 0..255
  const int xcd = bid & 7;                  // round-robin XCD id
  const int slot = bid >> 3;                // 0..31
  const int b = xcd >> 1;                   // 2 XCDs per batch
  const int sub = ((xcd & 1) << 5) | slot;  // 0..63 within batch
  const int i0 = sub * 4 + wave * 2;        // this wave: rows i0, i0+1

  float4 s0 = *(const float4*)&S0[((size_t)(b * Dc + i0)) * Dc + lane * 4];
  float4 s1 = *(const float4*)&S0[((size_t)(b * Dc + i0 + 1)) * Dc + lane * 4];

  const float* Kb = K + (size_t)b * Tc * Dc;
  const float* Qb = Q + (size_t)b * Tc * Dc;
  const float* Vb = V + (size_t)b * Tc * Dc;
  const float* Yb = ysc + (size_t)b * Tc * Dc;
  const float* bb_p = beta + (size_t)b * Tc;
  const float* kq_p = kq + (size_t)b * Tc;

  // PF-deep register buffers; k/q shared across the two chains.
  float4 kb[PF], qb[PF];
  float vb0[PF], vb1[PF], yv0[PF], yv1[PF], bbv[PF], kqb[PF];
#pragma unroll
  for (int j = 0; j < PF; ++j) {
    kb[j] = *(const float4*)&Kb[(size_t)j * Dc + lane * 4];
    qb[j] = *(const float4*)&Qb[(size_t)j * Dc + lane * 4];
    vb0[j] = Vb[(size_t)j * Dc + i0];
    vb1[j] = Vb[(size_t)j * Dc + i0 + 1];
    yv0[j] = Yb[(size_t)j * Dc + i0];
    yv1[j] = Yb[(size_t)j * Dc + i0 + 1];
    bbv[j] = bb_p[j];
    kqb[j] = kq_p[j];
  }

  for (int t0 = 0; t0 < Tc; t0 += PF) {
#pragma unroll
    for (int j = 0; j < PF; ++j) {
      const int t = t0 + j;
      const float4 k = kb[j];
      const float4 q = qb[j];
      const float v0 = vb0[j], v1 = vb1[j];
      const float y0 = yv0[j], y1 = yv1[j];
      const float bb = bbv[j];
      const float kqv = kqb[j];

      const int tn = (t + PF < Tc) ? t + PF : Tc - 1;
      kb[j] = *(const float4*)&Kb[(size_t)tn * Dc + lane * 4];
      qb[j] = *(const float4*)&Qb[(size_t)tn * Dc + lane * 4];
      vb0[j] = Vb[(size_t)tn * Dc + i0];
      vb1[j] = Vb[(size_t)tn * Dc + i0 + 1];
      yv0[j] = Yb[(size_t)tn * Dc + i0];
      yv1[j] = Yb[(size_t)tn * Dc + i0 + 1];
      bbv[j] = bb_p[tn];
      kqb[j] = kq_p[tn];

      float a0 = (s0.x * k.x + s0.y * k.y) + (s0.z * k.z + s0.w * k.w);
      float a1 = (s1.x * k.x + s1.y * k.y) + (s1.z * k.z + s1.w * k.w);
      float c0 = (s0.x * q.x + s0.y * q.y) + (s0.z * q.z + s0.w * q.w);
      float c1 = (s1.x * q.x + s1.y * q.y) + (s1.z * q.z + s1.w * q.w);
      wred4_dpp(a0, a1, c0, c1);

      const float w0 = bb * (v0 - a0);
      const float w1 = bb * (v1 - a1);
      s0.x = fmaf(w0, k.x, s0.x);
      s0.y = fmaf(w0, k.y, s0.y);
      s0.z = fmaf(w0, k.z, s0.z);
      s0.w = fmaf(w0, k.w, s0.w);
      s1.x = fmaf(w1, k.x, s1.x);
      s1.y = fmaf(w1, k.y, s1.y);
      s1.z = fmaf(w1, k.z, s1.z);
      s1.w = fmaf(w1, k.w, s1.w);

      floatx4 sv0, sv1;
      sv0.x = s0.x; sv0.y = s0.y; sv0.z = s0.z; sv0.w = s0.w;
      sv1.x = s1.x; sv1.y = s1.y; sv1.z = s1.z; sv1.w = s1.w;
      float* base = &states[(((size_t)b * Tc + t) * Dc + i0) * Dc + lane * 4];
      __builtin_nontemporal_store(sv0, (floatx4*)base);
      __builtin_nontemporal_store(sv1, (floatx4*)(base + Dc));
      if (lane == 0) {
        float* yb_ = &yout[((size_t)b * Tc + t) * Dc + i0];
        yb_[0] = c0 + w0 * kqv + y0;
        yb_[1] = c1 + w1 * kqv + y1;
      }
    }
  }
}

// ---------------------------------------------------------------------------
extern "C" void kernel_launch(void* const* d_in, const int* in_sizes, int n_in,
                              void* d_out, int out_size, void* d_ws,
                              size_t ws_size, hipStream_t stream) {
  const float* x = (const float*)d_in[0];
  const float* S0 = (const float*)d_in[1];
  const float* Wk = (const float*)d_in[2];
  const float* Wq = (const float*)d_in[3];
  const float* Wv = (const float*)d_in[4];
  const float* Wb = (const float*)d_in[5];
  const float* gamma = (const float*)d_in[6];
  const float* beta_ln = (const float*)d_in[7];
  const float* Wsc = (const float*)d_in[8];
  const float* bsc = (const float*)d_in[9];

  float* out = (float*)d_out;
  float* yout = out;                              // [B,T,D]
  float* states = out + (size_t)Bc * Tc * Dc;     // [B,T,D,D]

  const size_t BTD = (size_t)Bc * Tc * Dc;
  float* ws = (float*)d_ws;
  float* K = ws;
  float* Q = K + BTD;
  float* V = Q + BTD;
  float* ysc = V + BTD;
  float* beta = ysc + BTD;
  float* kq = beta + (size_t)Bc * Tc;

  proj_kernel<<<(Bc * Tc) / RPB, 256, 0, stream>>>(
      x, Wk, Wq, Wv, Wb, gamma, beta_ln, Wsc, bsc, K, Q, V, ysc, beta, kq);
  scan_kernel<<<256, 128, 0, stream>>>(S0, K, Q, V, ysc, beta, kq, yout,
                                       states);
}

// Round 9
// 217.263 us; speedup vs baseline: 1.1194x; 1.1194x over previous
//
#include <hip/hip_runtime.h>
#include <math.h>

#define Bc 4
#define Tc 512
#define Fc 512
#define Dc 256
#define RPB 8   // rows per block in projection kernel
#define CH 16   // scan LDS-staging chunk (timesteps)

typedef float floatx4 __attribute__((ext_vector_type(4)));

__device__ __forceinline__ float wred(float v) {
#pragma unroll
  for (int off = 32; off; off >>= 1) v += __shfl_xor(v, off, 64);
  return v;
}

// Dual wave64 sum-reduce via DPP (row_shr 1/2/4/8 + row_bcast 15/31).
__device__ __forceinline__ void wred2_dpp(float& a, float& c) {
#define DPP_STEP(ctrl, rmask)                                                 \
  {                                                                           \
    float ta = __int_as_float(__builtin_amdgcn_update_dpp(                    \
        0, __float_as_int(a), (ctrl), (rmask), 0xf, true));                   \
    float tc = __int_as_float(__builtin_amdgcn_update_dpp(                    \
        0, __float_as_int(c), (ctrl), (rmask), 0xf, true));                   \
    a += ta;                                                                  \
    c += tc;                                                                  \
  }
  DPP_STEP(0x111, 0xf)  // row_shr:1
  DPP_STEP(0x112, 0xf)  // row_shr:2
  DPP_STEP(0x114, 0xf)  // row_shr:4
  DPP_STEP(0x118, 0xf)  // row_shr:8
  DPP_STEP(0x142, 0xa)  // row_bcast:15 -> rows 1,3
  DPP_STEP(0x143, 0xc)  // row_bcast:31 -> rows 2,3
#undef DPP_STEP
  a = __int_as_float(__builtin_amdgcn_readlane(__float_as_int(a), 63));
  c = __int_as_float(__builtin_amdgcn_readlane(__float_as_int(c), 63));
}

// ---------------------------------------------------------------------------
// Kernel 1: LayerNorm + K/Q/V/beta/shortcut projections + sum-normalize + kq
// (exact R6 version — known-good 46 us; untouched this round)
// ---------------------------------------------------------------------------
__global__ __launch_bounds__(256) void proj_kernel(
    const float* __restrict__ x, const float* __restrict__ Wk,
    const float* __restrict__ Wq, const float* __restrict__ Wv,
    const float* __restrict__ Wb, const float* __restrict__ gamma,
    const float* __restrict__ beta_ln, const float* __restrict__ Wsc,
    const float* __restrict__ bsc, float* __restrict__ Ko,
    float* __restrict__ Qo, float* __restrict__ Vo, float* __restrict__ ysco,
    float* __restrict__ betao, float* __restrict__ kqo) {
  __shared__ __align__(16) float xn[RPB][Fc];
  __shared__ float red[4][32];
  __shared__ float fin[32];

  const int tid = threadIdx.x;
  const int wave = tid >> 6, lane = tid & 63;
  const int row0 = blockIdx.x * RPB;

#pragma unroll
  for (int rr = 0; rr < 2; ++rr) {
    const int r = wave * 2 + rr;
    const float* xr = x + (size_t)(row0 + r) * Fc;
    float4 a = *(const float4*)&xr[lane * 8];
    float4 b = *(const float4*)&xr[lane * 8 + 4];
    float s8 = a.x + a.y + a.z + a.w + b.x + b.y + b.z + b.w;
    float mu = wred(s8) * (1.0f / Fc);
    float d0 = a.x - mu, d1 = a.y - mu, d2 = a.z - mu, d3 = a.w - mu;
    float d4 = b.x - mu, d5 = b.y - mu, d6 = b.z - mu, d7 = b.w - mu;
    float sq = d0 * d0 + d1 * d1 + d2 * d2 + d3 * d3 + d4 * d4 + d5 * d5 +
               d6 * d6 + d7 * d7;
    float var = wred(sq) * (1.0f / Fc);
    float rs = rsqrtf(var + 1e-5f);
    float4 g0 = *(const float4*)&gamma[lane * 8];
    float4 g1 = *(const float4*)&gamma[lane * 8 + 4];
    float4 bl0 = *(const float4*)&beta_ln[lane * 8];
    float4 bl1 = *(const float4*)&beta_ln[lane * 8 + 4];
    float4 o0 = make_float4(d0 * rs * g0.x + bl0.x, d1 * rs * g0.y + bl0.y,
                            d2 * rs * g0.z + bl0.z, d3 * rs * g0.w + bl0.w);
    float4 o1 = make_float4(d4 * rs * g1.x + bl1.x, d5 * rs * g1.y + bl1.y,
                            d6 * rs * g1.z + bl1.z, d7 * rs * g1.w + bl1.w);
    *(float4*)&xn[r][lane * 8] = o0;
    *(float4*)&xn[r][lane * 8 + 4] = o1;
  }
  __syncthreads();

  const int d = tid;
  float accK[RPB], accQ[RPB], accV[RPB], accS[RPB];
#pragma unroll
  for (int r = 0; r < RPB; ++r) accK[r] = accQ[r] = accV[r] = accS[r] = 0.0f;

  for (int f = 0; f < Fc; f += 4) {
    float wk[4], wq[4], wv[4], ws[4];
#pragma unroll
    for (int ff = 0; ff < 4; ++ff) {
      wk[ff] = Wk[(size_t)(f + ff) * Dc + d];
      wq[ff] = Wq[(size_t)(f + ff) * Dc + d];
      wv[ff] = Wv[(size_t)(f + ff) * Dc + d];
      ws[ff] = Wsc[(size_t)(f + ff) * Dc + d];
    }
#pragma unroll
    for (int r = 0; r < RPB; ++r) {
      float4 xr = *(const float4*)&xn[r][f];
      accK[r] = fmaf(xr.w, wk[3], fmaf(xr.z, wk[2], fmaf(xr.y, wk[1], fmaf(xr.x, wk[0], accK[r]))));
      accQ[r] = fmaf(xr.w, wq[3], fmaf(xr.z, wq[2], fmaf(xr.y, wq[1], fmaf(xr.x, wq[0], accQ[r]))));
      accV[r] = fmaf(xr.w, wv[3], fmaf(xr.z, wv[2], fmaf(xr.y, wv[1], fmaf(xr.x, wv[0], accV[r]))));
      accS[r] = fmaf(xr.w, ws[3], fmaf(xr.z, ws[2], fmaf(xr.y, ws[1], fmaf(xr.x, ws[0], accS[r]))));
    }
  }

  float pk[RPB], pq[RPB];
#pragma unroll
  for (int r = 0; r < RPB; ++r) {
    pk[r] = fmaxf(accK[r], 0.0f);
    pq[r] = fmaxf(accQ[r], 0.0f);
  }
#pragma unroll
  for (int r = 0; r < RPB; ++r) {
    float p0 = wred(pk[r]);
    float p1 = wred(pq[r]);
    float p2 = wred(pk[r] * pq[r]);
    float pb = xn[r][tid] * Wb[tid] + xn[r][tid + 256] * Wb[tid + 256];
    float p3 = wred(pb);
    if (lane == 0) {
      red[wave][r * 4 + 0] = p0;
      red[wave][r * 4 + 1] = p1;
      red[wave][r * 4 + 2] = p2;
      red[wave][r * 4 + 3] = p3;
    }
  }
  __syncthreads();
  if (tid < 32) fin[tid] = red[0][tid] + red[1][tid] + red[2][tid] + red[3][tid];
  __syncthreads();

#pragma unroll
  for (int r = 0; r < RPB; ++r) {
    size_t row = (size_t)(row0 + r);
    float invK = 1.0f / (1e-5f + fin[r * 4 + 0]);
    float invQ = 1.0f / (1e-5f + fin[r * 4 + 1]);
    Ko[row * Dc + d] = pk[r] * invK;
    Qo[row * Dc + d] = pq[r] * invQ;
    Vo[row * Dc + d] = accV[r];
    ysco[row * Dc + d] = accS[r] + bsc[d];
  }
  if (tid < RPB) {
    size_t row = (size_t)(row0 + tid);
    float invK = 1.0f / (1e-5f + fin[tid * 4 + 0]);
    float invQ = 1.0f / (1e-5f + fin[tid * 4 + 1]);
    betao[row] = 1.0f / (1.0f + expf(-fin[tid * 4 + 3]));
    kqo[row] = fin[tid * 4 + 2] * invK * invQ;
  }
}

// ---------------------------------------------------------------------------
// Kernel 2: row-parallel state scan, LDS chunk staging (CH=16 steps).
// Main-loop operand reads are ds_read (lgkmcnt) -> DECOUPLED from the nt
// store stream's vmcnt. Previously, per-step global prefetch consumption
// waited on vmcnt, and vmcnt's in-issue-order decrement made every load
// wait transitively on an earlier store's ~900cy completion. Now stores are
// truly fire-and-forget; the only vmcnt(0) is at the per-chunk barrier
// (once/16 steps), which just synchronizes with the ongoing drain.
// Keeps: 1 wave per chain (R6), XCD swizzle (one batch per XCD -> 2 MB in
// 4 MB L2), nt stores (512 MB stream bypasses L2).
// ---------------------------------------------------------------------------
__global__ __launch_bounds__(256) void scan_kernel(
    const float* __restrict__ S0, const float* __restrict__ K,
    const float* __restrict__ Q, const float* __restrict__ V,
    const float* __restrict__ ysc, const float* __restrict__ beta,
    const float* __restrict__ kq, float* __restrict__ yout,
    float* __restrict__ states) {
  __shared__ __align__(16) float Ks[CH][Dc];  // 16 KB
  __shared__ __align__(16) float Qs[CH][Dc];  // 16 KB
  __shared__ float Vs[CH][4];
  __shared__ float Ys[CH][4];
  __shared__ float Bs[CH];
  __shared__ float KQs[CH];

  const int tid = threadIdx.x;
  const int wave = tid >> 6, lane = tid & 63;
  const int bid = blockIdx.x;               // 0..255
  const int xcd = bid & 7;                  // round-robin XCD id
  const int slot = bid >> 3;                // 0..31
  const int b = xcd >> 1;                   // 2 XCDs per batch
  const int sub = ((xcd & 1) << 5) | slot;  // 0..63 within batch
  const int i0 = sub * 4;                   // block's 4 chains: i0..i0+3
  const int i = i0 + wave;                  // this wave's state row

  float4 s = *(const float4*)&S0[((size_t)(b * Dc + i)) * Dc + lane * 4];

  const float* Kb = K + (size_t)b * Tc * Dc;
  const float* Qb = Q + (size_t)b * Tc * Dc;
  const float* Vb = V + (size_t)b * Tc * Dc;
  const float* Yb = ysc + (size_t)b * Tc * Dc;
  const float* bb_p = beta + (size_t)b * Tc;
  const float* kq_p = kq + (size_t)b * Tc;

  for (int c = 0; c < Tc / CH; ++c) {
    const int tb = c * CH;
    __syncthreads();  // all waves done reading previous chunk's LDS

    // ---- stage chunk: K,Q: 1024 float4s each, 4 per thread, coalesced ----
#pragma unroll
    for (int m = 0; m < 4; ++m) {
      const int f = tid + 256 * m;      // 0..1023
      const int row = f >> 6;           // 0..15
      const int c4 = f & 63;            // float4 col
      *(float4*)&Ks[row][c4 * 4] =
          *(const float4*)&Kb[(size_t)(tb + row) * Dc + c4 * 4];
      *(float4*)&Qs[row][c4 * 4] =
          *(const float4*)&Qb[(size_t)(tb + row) * Dc + c4 * 4];
    }
    if (tid < 64) {
      const int j = tid >> 2, w = tid & 3;
      Vs[j][w] = Vb[(size_t)(tb + j) * Dc + i0 + w];
    } else if (tid < 128) {
      const int j = (tid - 64) >> 2, w = tid & 3;
      Ys[j][w] = Yb[(size_t)(tb + j) * Dc + i0 + w];
    } else if (tid < 128 + CH) {
      Bs[tid - 128] = bb_p[tb + tid - 128];
    } else if (tid < 128 + 2 * CH) {
      KQs[tid - 128 - CH] = kq_p[tb + tid - 128 - CH];
    }
    __syncthreads();  // staging visible

    // ---- CH steps from LDS; stores fire-and-forget ----
#pragma unroll
    for (int j = 0; j < CH; ++j) {
      const float4 k = *(const float4*)&Ks[j][lane * 4];
      const float4 q = *(const float4*)&Qs[j][lane * 4];
      const float vv = Vs[j][wave];
      const float yb = Ys[j][wave];
      const float bb = Bs[j];
      const float kqv = KQs[j];

      float a = (s.x * k.x + s.y * k.y) + (s.z * k.z + s.w * k.w);
      float c2 = (s.x * q.x + s.y * q.y) + (s.z * q.z + s.w * q.w);
      wred2_dpp(a, c2);

      const float w = bb * (vv - a);
      s.x = fmaf(w, k.x, s.x);
      s.y = fmaf(w, k.y, s.y);
      s.z = fmaf(w, k.z, s.z);
      s.w = fmaf(w, k.w, s.w);

      floatx4 sv;
      sv.x = s.x; sv.y = s.y; sv.z = s.z; sv.w = s.w;
      __builtin_nontemporal_store(
          sv, (floatx4*)&states[(((size_t)b * Tc + tb + j) * Dc + i) * Dc +
                                lane * 4]);
      if (lane == 0)
        yout[((size_t)b * Tc + tb + j) * Dc + i] = c2 + w * kqv + yb;
    }
  }
}

// ---------------------------------------------------------------------------
extern "C" void kernel_launch(void* const* d_in, const int* in_sizes, int n_in,
                              void* d_out, int out_size, void* d_ws,
                              size_t ws_size, hipStream_t stream) {
  const float* x = (const float*)d_in[0];
  const float* S0 = (const float*)d_in[1];
  const float* Wk = (const float*)d_in[2];
  const float* Wq = (const float*)d_in[3];
  const float* Wv = (const float*)d_in[4];
  const float* Wb = (const float*)d_in[5];
  const float* gamma = (const float*)d_in[6];
  const float* beta_ln = (const float*)d_in[7];
  const float* Wsc = (const float*)d_in[8];
  const float* bsc = (const float*)d_in[9];

  float* out = (float*)d_out;
  float* yout = out;                              // [B,T,D]
  float* states = out + (size_t)Bc * Tc * Dc;     // [B,T,D,D]

  const size_t BTD = (size_t)Bc * Tc * Dc;
  float* ws = (float*)d_ws;
  float* K = ws;
  float* Q = K + BTD;
  float* V = Q + BTD;
  float* ysc = V + BTD;
  float* beta = ysc + BTD;
  float* kq = beta + (size_t)Bc * Tc;

  proj_kernel<<<(Bc * Tc) / RPB, 256, 0, stream>>>(
      x, Wk, Wq, Wv, Wb, gamma, beta_ln, Wsc, bsc, K, Q, V, ysc, beta, kq);
  scan_kernel<<<(Bc * Dc) / 4, 256, 0, stream>>>(S0, K, Q, V, ysc, beta, kq,
                                                 yout, states);
}

// Round 10
// 173.381 us; speedup vs baseline: 1.4028x; 1.2531x over previous
//
#include <hip/hip_runtime.h>
#include <math.h>

#define Bc 4
#define Tc 512
#define Fc 512
#define Dc 256
#define RPB 8   // rows per block in projection kernel
#define PF 4    // A-wave global prefetch depth
#define CH 16   // ring chunk (timesteps)
#define RS 2    // ring slots (chunks)

typedef float floatx4 __attribute__((ext_vector_type(4)));

__device__ __forceinline__ float wred(float v) {
#pragma unroll
  for (int off = 32; off; off >>= 1) v += __shfl_xor(v, off, 64);
  return v;
}

// Dual wave64 sum-reduce via DPP (row_shr 1/2/4/8 + row_bcast 15/31).
__device__ __forceinline__ void wred2_dpp(float& a, float& c) {
#define DPP_STEP(ctrl, rmask)                                                 \
  {                                                                           \
    float ta = __int_as_float(__builtin_amdgcn_update_dpp(                    \
        0, __float_as_int(a), (ctrl), (rmask), 0xf, true));                   \
    float tc = __int_as_float(__builtin_amdgcn_update_dpp(                    \
        0, __float_as_int(c), (ctrl), (rmask), 0xf, true));                   \
    a += ta;                                                                  \
    c += tc;                                                                  \
  }
  DPP_STEP(0x111, 0xf)  // row_shr:1
  DPP_STEP(0x112, 0xf)  // row_shr:2
  DPP_STEP(0x114, 0xf)  // row_shr:4
  DPP_STEP(0x118, 0xf)  // row_shr:8
  DPP_STEP(0x142, 0xa)  // row_bcast:15 -> rows 1,3
  DPP_STEP(0x143, 0xc)  // row_bcast:31 -> rows 2,3
#undef DPP_STEP
  a = __int_as_float(__builtin_amdgcn_readlane(__float_as_int(a), 63));
  c = __int_as_float(__builtin_amdgcn_readlane(__float_as_int(c), 63));
}

// ---------------------------------------------------------------------------
// Kernel 1: LayerNorm + K/Q/V/beta/shortcut projections + sum-normalize + kq
// (exact R6 version — known-good; untouched)
// ---------------------------------------------------------------------------
__global__ __launch_bounds__(256) void proj_kernel(
    const float* __restrict__ x, const float* __restrict__ Wk,
    const float* __restrict__ Wq, const float* __restrict__ Wv,
    const float* __restrict__ Wb, const float* __restrict__ gamma,
    const float* __restrict__ beta_ln, const float* __restrict__ Wsc,
    const float* __restrict__ bsc, float* __restrict__ Ko,
    float* __restrict__ Qo, float* __restrict__ Vo, float* __restrict__ ysco,
    float* __restrict__ betao, float* __restrict__ kqo) {
  __shared__ __align__(16) float xn[RPB][Fc];
  __shared__ float red[4][32];
  __shared__ float fin[32];

  const int tid = threadIdx.x;
  const int wave = tid >> 6, lane = tid & 63;
  const int row0 = blockIdx.x * RPB;

#pragma unroll
  for (int rr = 0; rr < 2; ++rr) {
    const int r = wave * 2 + rr;
    const float* xr = x + (size_t)(row0 + r) * Fc;
    float4 a = *(const float4*)&xr[lane * 8];
    float4 b = *(const float4*)&xr[lane * 8 + 4];
    float s8 = a.x + a.y + a.z + a.w + b.x + b.y + b.z + b.w;
    float mu = wred(s8) * (1.0f / Fc);
    float d0 = a.x - mu, d1 = a.y - mu, d2 = a.z - mu, d3 = a.w - mu;
    float d4 = b.x - mu, d5 = b.y - mu, d6 = b.z - mu, d7 = b.w - mu;
    float sq = d0 * d0 + d1 * d1 + d2 * d2 + d3 * d3 + d4 * d4 + d5 * d5 +
               d6 * d6 + d7 * d7;
    float var = wred(sq) * (1.0f / Fc);
    float rs = rsqrtf(var + 1e-5f);
    float4 g0 = *(const float4*)&gamma[lane * 8];
    float4 g1 = *(const float4*)&gamma[lane * 8 + 4];
    float4 bl0 = *(const float4*)&beta_ln[lane * 8];
    float4 bl1 = *(const float4*)&beta_ln[lane * 8 + 4];
    float4 o0 = make_float4(d0 * rs * g0.x + bl0.x, d1 * rs * g0.y + bl0.y,
                            d2 * rs * g0.z + bl0.z, d3 * rs * g0.w + bl0.w);
    float4 o1 = make_float4(d4 * rs * g1.x + bl1.x, d5 * rs * g1.y + bl1.y,
                            d6 * rs * g1.z + bl1.z, d7 * rs * g1.w + bl1.w);
    *(float4*)&xn[r][lane * 8] = o0;
    *(float4*)&xn[r][lane * 8 + 4] = o1;
  }
  __syncthreads();

  const int d = tid;
  float accK[RPB], accQ[RPB], accV[RPB], accS[RPB];
#pragma unroll
  for (int r = 0; r < RPB; ++r) accK[r] = accQ[r] = accV[r] = accS[r] = 0.0f;

  for (int f = 0; f < Fc; f += 4) {
    float wk[4], wq[4], wv[4], ws[4];
#pragma unroll
    for (int ff = 0; ff < 4; ++ff) {
      wk[ff] = Wk[(size_t)(f + ff) * Dc + d];
      wq[ff] = Wq[(size_t)(f + ff) * Dc + d];
      wv[ff] = Wv[(size_t)(f + ff) * Dc + d];
      ws[ff] = Wsc[(size_t)(f + ff) * Dc + d];
    }
#pragma unroll
    for (int r = 0; r < RPB; ++r) {
      float4 xr = *(const float4*)&xn[r][f];
      accK[r] = fmaf(xr.w, wk[3], fmaf(xr.z, wk[2], fmaf(xr.y, wk[1], fmaf(xr.x, wk[0], accK[r]))));
      accQ[r] = fmaf(xr.w, wq[3], fmaf(xr.z, wq[2], fmaf(xr.y, wq[1], fmaf(xr.x, wq[0], accQ[r]))));
      accV[r] = fmaf(xr.w, wv[3], fmaf(xr.z, wv[2], fmaf(xr.y, wv[1], fmaf(xr.x, wv[0], accV[r]))));
      accS[r] = fmaf(xr.w, ws[3], fmaf(xr.z, ws[2], fmaf(xr.y, ws[1], fmaf(xr.x, ws[0], accS[r]))));
    }
  }

  float pk[RPB], pq[RPB];
#pragma unroll
  for (int r = 0; r < RPB; ++r) {
    pk[r] = fmaxf(accK[r], 0.0f);
    pq[r] = fmaxf(accQ[r], 0.0f);
  }
#pragma unroll
  for (int r = 0; r < RPB; ++r) {
    float p0 = wred(pk[r]);
    float p1 = wred(pq[r]);
    float p2 = wred(pk[r] * pq[r]);
    float pb = xn[r][tid] * Wb[tid] + xn[r][tid + 256] * Wb[tid + 256];
    float p3 = wred(pb);
    if (lane == 0) {
      red[wave][r * 4 + 0] = p0;
      red[wave][r * 4 + 1] = p1;
      red[wave][r * 4 + 2] = p2;
      red[wave][r * 4 + 3] = p3;
    }
  }
  __syncthreads();
  if (tid < 32) fin[tid] = red[0][tid] + red[1][tid] + red[2][tid] + red[3][tid];
  __syncthreads();

#pragma unroll
  for (int r = 0; r < RPB; ++r) {
    size_t row = (size_t)(row0 + r);
    float invK = 1.0f / (1e-5f + fin[r * 4 + 0]);
    float invQ = 1.0f / (1e-5f + fin[r * 4 + 1]);
    Ko[row * Dc + d] = pk[r] * invK;
    Qo[row * Dc + d] = pq[r] * invQ;
    Vo[row * Dc + d] = accV[r];
    ysco[row * Dc + d] = accS[r] + bsc[d];
  }
  if (tid < RPB) {
    size_t row = (size_t)(row0 + tid);
    float invK = 1.0f / (1e-5f + fin[tid * 4 + 0]);
    float invQ = 1.0f / (1e-5f + fin[tid * 4 + 1]);
    betao[row] = 1.0f / (1.0f + expf(-fin[tid * 4 + 3]));
    kqo[row] = fin[tid * 4 + 2] * invK * invQ;
  }
}

// ---------------------------------------------------------------------------
// Kernel 2: fused producer/consumer scan. 256 blocks x 512 threads (8 waves,
// 1 block/CU). Waves 0-3 ("A"): R6 recurrence chain for rows i0..i0+3 —
// dots, DPP reduce, y output — publishing u_t (=w) and k_t into an LDS ring
// (no states stores -> no store-queue backpressure on the chain). Waves 4-7
// ("B"): per matching row, replay S_t = S + u_t k_t^T from the ring (ds_read
// + 4 FMA + nt store, no reduces, no global-load waits) -> a pure store
// stream that paces at drain rate like fillBufferAligned's 6.5 TB/s.
// B's trajectory is bit-identical to A's (same fmaf/operands/order).
// Chunk-granular acquire/release flags, s_sleep polling, block-local only.
// XCD swizzle: one batch per XCD (2 MB K/Q in its 4 MB L2).
// ---------------------------------------------------------------------------
__global__ __launch_bounds__(512) void scan_kernel(
    const float* __restrict__ S0, const float* __restrict__ K,
    const float* __restrict__ Q, const float* __restrict__ V,
    const float* __restrict__ ysc, const float* __restrict__ beta,
    const float* __restrict__ kq, float* __restrict__ yout,
    float* __restrict__ states) {
  __shared__ __align__(16) float ring_k[RS][CH][Dc];  // 32 KB
  __shared__ float ring_u[RS][CH][4];                 // 512 B
  __shared__ int prog_a[4];  // chunks published per A-wave
  __shared__ int prog_b[4];  // chunks consumed per B-wave

  const int tid = threadIdx.x;
  const int wave = tid >> 6, lane = tid & 63;
  const int bid = blockIdx.x;               // 0..255
  const int xcd = bid & 7;                  // round-robin XCD id
  const int slot = bid >> 3;                // 0..31
  const int b = xcd >> 1;                   // 2 XCDs per batch
  const int sub = ((xcd & 1) << 5) | slot;  // 0..63 within batch
  const int i0 = sub * 4;                   // block rows: i0..i0+3

  if (tid < 4) {
    prog_a[tid] = 0;
    prog_b[tid] = 0;
  }
  __syncthreads();

  if (wave < 4) {
    // ======================= A: recurrence producer ========================
    const int i = i0 + wave;
    float4 s = *(const float4*)&S0[((size_t)(b * Dc + i)) * Dc + lane * 4];

    const float* Kb = K + (size_t)b * Tc * Dc;
    const float* Qb = Q + (size_t)b * Tc * Dc;
    const float* Vb = V + (size_t)b * Tc * Dc;
    const float* Yb = ysc + (size_t)b * Tc * Dc;
    const float* bb_p = beta + (size_t)b * Tc;
    const float* kq_p = kq + (size_t)b * Tc;

    float4 kb[PF], qb[PF];
    float vb[PF], ybv[PF], bbv[PF], kqb[PF];
#pragma unroll
    for (int j = 0; j < PF; ++j) {
      kb[j] = *(const float4*)&Kb[(size_t)j * Dc + lane * 4];
      qb[j] = *(const float4*)&Qb[(size_t)j * Dc + lane * 4];
      vb[j] = Vb[(size_t)j * Dc + i];
      ybv[j] = Yb[(size_t)j * Dc + i];
      bbv[j] = bb_p[j];
      kqb[j] = kq_p[j];
    }

    for (int c = 0; c < Tc / CH; ++c) {
      // Before overwriting ring slot c%RS, ensure every B-wave consumed
      // chunk c-RS (wave 0's k feeds all four B chains).
      if (c >= RS) {
        const int need = c - RS + 1;
#pragma unroll
        for (int m = 0; m < 4; ++m) {
          while (__hip_atomic_load(&prog_b[m], __ATOMIC_ACQUIRE,
                                   __HIP_MEMORY_SCOPE_WORKGROUP) < need)
            __builtin_amdgcn_s_sleep(2);
        }
      }
      const int r = c & (RS - 1);
      const int tb = c * CH;

      for (int t0 = tb; t0 < tb + CH; t0 += PF) {
#pragma unroll
        for (int p = 0; p < PF; ++p) {
          const int t = t0 + p;
          const float4 k = kb[p];
          const float4 q = qb[p];
          const float vv = vb[p];
          const float yb = ybv[p];
          const float bbs = bbv[p];
          const float kqv = kqb[p];

          const int tn = (t + PF < Tc) ? t + PF : Tc - 1;
          kb[p] = *(const float4*)&Kb[(size_t)tn * Dc + lane * 4];
          qb[p] = *(const float4*)&Qb[(size_t)tn * Dc + lane * 4];
          vb[p] = Vb[(size_t)tn * Dc + i];
          ybv[p] = Yb[(size_t)tn * Dc + i];
          bbv[p] = bb_p[tn];
          kqb[p] = kq_p[tn];

          float a = (s.x * k.x + s.y * k.y) + (s.z * k.z + s.w * k.w);
          float c2 = (s.x * q.x + s.y * q.y) + (s.z * q.z + s.w * q.w);
          wred2_dpp(a, c2);

          const float wcoef = bbs * (vv - a);
          s.x = fmaf(wcoef, k.x, s.x);
          s.y = fmaf(wcoef, k.y, s.y);
          s.z = fmaf(wcoef, k.z, s.z);
          s.w = fmaf(wcoef, k.w, s.w);

          const int j = t - tb;
          if (wave == 0) *(float4*)&ring_k[r][j][lane * 4] = k;
          if (lane == 0) {
            ring_u[r][j][wave] = wcoef;
            yout[((size_t)b * Tc + t) * Dc + i] = c2 + wcoef * kqv + yb;
          }
        }
      }
      __threadfence_block();
      __hip_atomic_store(&prog_a[wave], c + 1, __ATOMIC_RELEASE,
                         __HIP_MEMORY_SCOPE_WORKGROUP);
    }
  } else {
    // ======================= B: states store stream ========================
    const int wv = wave - 4;
    const int i = i0 + wv;
    float4 s = *(const float4*)&S0[((size_t)(b * Dc + i)) * Dc + lane * 4];

    for (int c = 0; c < Tc / CH; ++c) {
      const int need = c + 1;
      while (__hip_atomic_load(&prog_a[wv], __ATOMIC_ACQUIRE,
                               __HIP_MEMORY_SCOPE_WORKGROUP) < need)
        __builtin_amdgcn_s_sleep(2);
      while (__hip_atomic_load(&prog_a[0], __ATOMIC_ACQUIRE,
                               __HIP_MEMORY_SCOPE_WORKGROUP) < need)
        __builtin_amdgcn_s_sleep(2);

      const int r = c & (RS - 1);
      const int tb = c * CH;
#pragma unroll
      for (int j = 0; j < CH; ++j) {
        const float u = ring_u[r][j][wv];
        const float4 k = *(const float4*)&ring_k[r][j][lane * 4];
        s.x = fmaf(u, k.x, s.x);
        s.y = fmaf(u, k.y, s.y);
        s.z = fmaf(u, k.z, s.z);
        s.w = fmaf(u, k.w, s.w);
        floatx4 sv;
        sv.x = s.x; sv.y = s.y; sv.z = s.z; sv.w = s.w;
        __builtin_nontemporal_store(
            sv, (floatx4*)&states[(((size_t)b * Tc + tb + j) * Dc + i) * Dc +
                                  lane * 4]);
      }
      __threadfence_block();
      __hip_atomic_store(&prog_b[wv], c + 1, __ATOMIC_RELEASE,
                         __HIP_MEMORY_SCOPE_WORKGROUP);
    }
  }
}

// ---------------------------------------------------------------------------
extern "C" void kernel_launch(void* const* d_in, const int* in_sizes, int n_in,
                              void* d_out, int out_size, void* d_ws,
                              size_t ws_size, hipStream_t stream) {
  const float* x = (const float*)d_in[0];
  const float* S0 = (const float*)d_in[1];
  const float* Wk = (const float*)d_in[2];
  const float* Wq = (const float*)d_in[3];
  const float* Wv = (const float*)d_in[4];
  const float* Wb = (const float*)d_in[5];
  const float* gamma = (const float*)d_in[6];
  const float* beta_ln = (const float*)d_in[7];
  const float* Wsc = (const float*)d_in[8];
  const float* bsc = (const float*)d_in[9];

  float* out = (float*)d_out;
  float* yout = out;                              // [B,T,D]
  float* states = out + (size_t)Bc * Tc * Dc;     // [B,T,D,D]

  const size_t BTD = (size_t)Bc * Tc * Dc;
  float* ws = (float*)d_ws;
  float* K = ws;
  float* Q = K + BTD;
  float* V = Q + BTD;
  float* ysc = V + BTD;
  float* beta = ysc + BTD;
  float* kq = beta + (size_t)Bc * Tc;

  proj_kernel<<<(Bc * Tc) / RPB, 256, 0, stream>>>(
      x, Wk, Wq, Wv, Wb, gamma, beta_ln, Wsc, bsc, K, Q, V, ysc, beta, kq);
  scan_kernel<<<(Bc * Dc) / 4, 512, 0, stream>>>(S0, K, Q, V, ysc, beta, kq,
                                                 yout, states);
}

// Round 11
// 155.738 us; speedup vs baseline: 1.5617x; 1.1133x over previous
//
#include <hip/hip_runtime.h>
#include <math.h>

#define Bc 4
#define Tc 512
#define Fc 512
#define Dc 256
#define RPB 8   // rows per block in projection kernel
#define PF 4    // A-wave k/q prefetch depth
#define CH 16   // ring chunk (timesteps)
#define RS 4    // ring slots (chunks)
#define NC (Tc / CH)

typedef float floatx4 __attribute__((ext_vector_type(4)));

__device__ __forceinline__ float wred(float v) {
#pragma unroll
  for (int off = 32; off; off >>= 1) v += __shfl_xor(v, off, 64);
  return v;
}

__device__ __forceinline__ float rl(float v, int l) {
  return __int_as_float(__builtin_amdgcn_readlane(__float_as_int(v), l));
}

// Dual wave64 sum-reduce via DPP (row_shr 1/2/4/8 + row_bcast 15/31).
__device__ __forceinline__ void wred2_dpp(float& a, float& c) {
#define DPP_STEP(ctrl, rmask)                                                 \
  {                                                                           \
    float ta = __int_as_float(__builtin_amdgcn_update_dpp(                    \
        0, __float_as_int(a), (ctrl), (rmask), 0xf, true));                   \
    float tc = __int_as_float(__builtin_amdgcn_update_dpp(                    \
        0, __float_as_int(c), (ctrl), (rmask), 0xf, true));                   \
    a += ta;                                                                  \
    c += tc;                                                                  \
  }
  DPP_STEP(0x111, 0xf)  // row_shr:1
  DPP_STEP(0x112, 0xf)  // row_shr:2
  DPP_STEP(0x114, 0xf)  // row_shr:4
  DPP_STEP(0x118, 0xf)  // row_shr:8
  DPP_STEP(0x142, 0xa)  // row_bcast:15 -> rows 1,3
  DPP_STEP(0x143, 0xc)  // row_bcast:31 -> rows 2,3
#undef DPP_STEP
  a = rl(a, 63);
  c = rl(c, 63);
}

// ---------------------------------------------------------------------------
// Kernel 1: LayerNorm + K/Q/V/beta/shortcut projections + sum-normalize + kq
// (exact R6 version — known-good; untouched)
// ---------------------------------------------------------------------------
__global__ __launch_bounds__(256) void proj_kernel(
    const float* __restrict__ x, const float* __restrict__ Wk,
    const float* __restrict__ Wq, const float* __restrict__ Wv,
    const float* __restrict__ Wb, const float* __restrict__ gamma,
    const float* __restrict__ beta_ln, const float* __restrict__ Wsc,
    const float* __restrict__ bsc, float* __restrict__ Ko,
    float* __restrict__ Qo, float* __restrict__ Vo, float* __restrict__ ysco,
    float* __restrict__ betao, float* __restrict__ kqo) {
  __shared__ __align__(16) float xn[RPB][Fc];
  __shared__ float red[4][32];
  __shared__ float fin[32];

  const int tid = threadIdx.x;
  const int wave = tid >> 6, lane = tid & 63;
  const int row0 = blockIdx.x * RPB;

#pragma unroll
  for (int rr = 0; rr < 2; ++rr) {
    const int r = wave * 2 + rr;
    const float* xr = x + (size_t)(row0 + r) * Fc;
    float4 a = *(const float4*)&xr[lane * 8];
    float4 b = *(const float4*)&xr[lane * 8 + 4];
    float s8 = a.x + a.y + a.z + a.w + b.x + b.y + b.z + b.w;
    float mu = wred(s8) * (1.0f / Fc);
    float d0 = a.x - mu, d1 = a.y - mu, d2 = a.z - mu, d3 = a.w - mu;
    float d4 = b.x - mu, d5 = b.y - mu, d6 = b.z - mu, d7 = b.w - mu;
    float sq = d0 * d0 + d1 * d1 + d2 * d2 + d3 * d3 + d4 * d4 + d5 * d5 +
               d6 * d6 + d7 * d7;
    float var = wred(sq) * (1.0f / Fc);
    float rs = rsqrtf(var + 1e-5f);
    float4 g0 = *(const float4*)&gamma[lane * 8];
    float4 g1 = *(const float4*)&gamma[lane * 8 + 4];
    float4 bl0 = *(const float4*)&beta_ln[lane * 8];
    float4 bl1 = *(const float4*)&beta_ln[lane * 8 + 4];
    float4 o0 = make_float4(d0 * rs * g0.x + bl0.x, d1 * rs * g0.y + bl0.y,
                            d2 * rs * g0.z + bl0.z, d3 * rs * g0.w + bl0.w);
    float4 o1 = make_float4(d4 * rs * g1.x + bl1.x, d5 * rs * g1.y + bl1.y,
                            d6 * rs * g1.z + bl1.z, d7 * rs * g1.w + bl1.w);
    *(float4*)&xn[r][lane * 8] = o0;
    *(float4*)&xn[r][lane * 8 + 4] = o1;
  }
  __syncthreads();

  const int d = tid;
  float accK[RPB], accQ[RPB], accV[RPB], accS[RPB];
#pragma unroll
  for (int r = 0; r < RPB; ++r) accK[r] = accQ[r] = accV[r] = accS[r] = 0.0f;

  for (int f = 0; f < Fc; f += 4) {
    float wk[4], wq[4], wv[4], ws[4];
#pragma unroll
    for (int ff = 0; ff < 4; ++ff) {
      wk[ff] = Wk[(size_t)(f + ff) * Dc + d];
      wq[ff] = Wq[(size_t)(f + ff) * Dc + d];
      wv[ff] = Wv[(size_t)(f + ff) * Dc + d];
      ws[ff] = Wsc[(size_t)(f + ff) * Dc + d];
    }
#pragma unroll
    for (int r = 0; r < RPB; ++r) {
      float4 xr = *(const float4*)&xn[r][f];
      accK[r] = fmaf(xr.w, wk[3], fmaf(xr.z, wk[2], fmaf(xr.y, wk[1], fmaf(xr.x, wk[0], accK[r]))));
      accQ[r] = fmaf(xr.w, wq[3], fmaf(xr.z, wq[2], fmaf(xr.y, wq[1], fmaf(xr.x, wq[0], accQ[r]))));
      accV[r] = fmaf(xr.w, wv[3], fmaf(xr.z, wv[2], fmaf(xr.y, wv[1], fmaf(xr.x, wv[0], accV[r]))));
      accS[r] = fmaf(xr.w, ws[3], fmaf(xr.z, ws[2], fmaf(xr.y, ws[1], fmaf(xr.x, ws[0], accS[r]))));
    }
  }

  float pk[RPB], pq[RPB];
#pragma unroll
  for (int r = 0; r < RPB; ++r) {
    pk[r] = fmaxf(accK[r], 0.0f);
    pq[r] = fmaxf(accQ[r], 0.0f);
  }
#pragma unroll
  for (int r = 0; r < RPB; ++r) {
    float p0 = wred(pk[r]);
    float p1 = wred(pq[r]);
    float p2 = wred(pk[r] * pq[r]);
    float pb = xn[r][tid] * Wb[tid] + xn[r][tid + 256] * Wb[tid + 256];
    float p3 = wred(pb);
    if (lane == 0) {
      red[wave][r * 4 + 0] = p0;
      red[wave][r * 4 + 1] = p1;
      red[wave][r * 4 + 2] = p2;
      red[wave][r * 4 + 3] = p3;
    }
  }
  __syncthreads();
  if (tid < 32) fin[tid] = red[0][tid] + red[1][tid] + red[2][tid] + red[3][tid];
  __syncthreads();

#pragma unroll
  for (int r = 0; r < RPB; ++r) {
    size_t row = (size_t)(row0 + r);
    float invK = 1.0f / (1e-5f + fin[r * 4 + 0]);
    float invQ = 1.0f / (1e-5f + fin[r * 4 + 1]);
    Ko[row * Dc + d] = pk[r] * invK;
    Qo[row * Dc + d] = pq[r] * invQ;
    Vo[row * Dc + d] = accV[r];
    ysco[row * Dc + d] = accS[r] + bsc[d];
  }
  if (tid < RPB) {
    size_t row = (size_t)(row0 + tid);
    float invK = 1.0f / (1e-5f + fin[tid * 4 + 0]);
    float invQ = 1.0f / (1e-5f + fin[tid * 4 + 1]);
    betao[row] = 1.0f / (1.0f + expf(-fin[tid * 4 + 3]));
    kqo[row] = fin[tid * 4 + 2] * invK * invQ;
  }
}

// ---------------------------------------------------------------------------
// Kernel 2: producer/consumer scan, A = PURE-LOAD recurrence wave.
// vs R10: (1) A's y output moved into the ring (float2 u,y); B stores y ->
// A issues ZERO global stores, so its pure-load vmcnt queue never waits on
// store completion. (2) v/ysc/beta/kq loaded once per chunk via lane-indexed
// loads + readlane (4 loads/chunk vs 64), prefetched one chunk ahead.
// (3) ring_k write spread across A-waves (wave j&3 writes step j).
// (4) RS=4 slots (66 KB LDS) so A runs up to 3 chunks ahead.
// B unchanged: drain-paced pure store stream (+1 tiny y store/step).
// ---------------------------------------------------------------------------
__global__ __launch_bounds__(512) void scan_kernel(
    const float* __restrict__ S0, const float* __restrict__ K,
    const float* __restrict__ Q, const float* __restrict__ V,
    const float* __restrict__ ysc, const float* __restrict__ beta,
    const float* __restrict__ kq, float* __restrict__ yout,
    float* __restrict__ states) {
  __shared__ __align__(16) float ring_k[RS][CH][Dc];  // 64 KB
  __shared__ float2 ring_uy[RS][CH][4];               // 2 KB
  __shared__ int prog_a[4];
  __shared__ int prog_b[4];

  const int tid = threadIdx.x;
  const int wave = tid >> 6, lane = tid & 63;
  const int bid = blockIdx.x;               // 0..255
  const int xcd = bid & 7;                  // round-robin XCD id
  const int slot = bid >> 3;                // 0..31
  const int b = xcd >> 1;                   // 2 XCDs per batch
  const int sub = ((xcd & 1) << 5) | slot;  // 0..63 within batch
  const int i0 = sub * 4;                   // block rows: i0..i0+3

  if (tid < 4) {
    prog_a[tid] = 0;
    prog_b[tid] = 0;
  }
  __syncthreads();

  if (wave < 4) {
    // ======================= A: recurrence producer ========================
    const int i = i0 + wave;
    float4 s = *(const float4*)&S0[((size_t)(b * Dc + i)) * Dc + lane * 4];

    const float* Kb = K + (size_t)b * Tc * Dc;
    const float* Qb = Q + (size_t)b * Tc * Dc;
    const float* Vb = V + (size_t)b * Tc * Dc;
    const float* Yb = ysc + (size_t)b * Tc * Dc;
    const float* bb_p = beta + (size_t)b * Tc;
    const float* kq_p = kq + (size_t)b * Tc;

    // k/q PF-deep circular register prefetch
    float4 kb[PF], qb[PF];
#pragma unroll
    for (int j = 0; j < PF; ++j) {
      kb[j] = *(const float4*)&Kb[(size_t)j * Dc + lane * 4];
      qb[j] = *(const float4*)&Qb[(size_t)j * Dc + lane * 4];
    }
    // chunk-0 scalars: lane j holds step-j values (j = lane & 15)
    const int sl = lane & 15;
    float vcur = Vb[(size_t)sl * Dc + i];
    float ycur = Yb[(size_t)sl * Dc + i];
    float bcur = bb_p[sl];
    float kqcur = kq_p[sl];

    for (int c = 0; c < NC; ++c) {
      // ring-space: every B must have consumed chunk c-RS
      if (c >= RS) {
        const int need = c - RS + 1;
#pragma unroll
        for (int m = 0; m < 4; ++m) {
          while (__hip_atomic_load(&prog_b[m], __ATOMIC_ACQUIRE,
                                   __HIP_MEMORY_SCOPE_WORKGROUP) < need)
            __builtin_amdgcn_s_sleep(2);
        }
      }
      // prefetch next chunk's scalars (consumed after this chunk)
      const int cn = (c + 1 < NC) ? c + 1 : c;
      const int tbn = cn * CH;
      float vnxt = Vb[(size_t)(tbn + sl) * Dc + i];
      float ynxt = Yb[(size_t)(tbn + sl) * Dc + i];
      float bnxt = bb_p[tbn + sl];
      float kqnxt = kq_p[tbn + sl];

      const int r = c & (RS - 1);
      const int tb = c * CH;
#pragma unroll
      for (int j = 0; j < CH; ++j) {
        const int t = tb + j;
        const float4 k = kb[j & (PF - 1)];
        const float4 q = qb[j & (PF - 1)];
        const float vv = rl(vcur, j);
        const float yb = rl(ycur, j);
        const float bbs = rl(bcur, j);
        const float kqv = rl(kqcur, j);

        const int tn = (t + PF < Tc) ? t + PF : Tc - 1;
        kb[j & (PF - 1)] = *(const float4*)&Kb[(size_t)tn * Dc + lane * 4];
        qb[j & (PF - 1)] = *(const float4*)&Qb[(size_t)tn * Dc + lane * 4];

        float a = (s.x * k.x + s.y * k.y) + (s.z * k.z + s.w * k.w);
        float c2 = (s.x * q.x + s.y * q.y) + (s.z * q.z + s.w * q.w);
        wred2_dpp(a, c2);

        const float wcoef = bbs * (vv - a);
        s.x = fmaf(wcoef, k.x, s.x);
        s.y = fmaf(wcoef, k.y, s.y);
        s.z = fmaf(wcoef, k.z, s.z);
        s.w = fmaf(wcoef, k.w, s.w);

        if (wave == (j & 3)) *(float4*)&ring_k[r][j][lane * 4] = k;
        if (lane == 0) {
          float2 uy;
          uy.x = wcoef;
          uy.y = c2 + wcoef * kqv + yb;
          ring_uy[r][j][wave] = uy;
        }
      }
      __threadfence_block();
      __hip_atomic_store(&prog_a[wave], c + 1, __ATOMIC_RELEASE,
                         __HIP_MEMORY_SCOPE_WORKGROUP);
      vcur = vnxt;
      ycur = ynxt;
      bcur = bnxt;
      kqcur = kqnxt;
    }
  } else {
    // ======================= B: states store stream ========================
    const int wv = wave - 4;
    const int i = i0 + wv;
    float4 s = *(const float4*)&S0[((size_t)(b * Dc + i)) * Dc + lane * 4];

    for (int c = 0; c < NC; ++c) {
      const int need = c + 1;
#pragma unroll
      for (int m = 0; m < 4; ++m) {
        while (__hip_atomic_load(&prog_a[m], __ATOMIC_ACQUIRE,
                                 __HIP_MEMORY_SCOPE_WORKGROUP) < need)
          __builtin_amdgcn_s_sleep(2);
      }

      const int r = c & (RS - 1);
      const int tb = c * CH;
#pragma unroll
      for (int j = 0; j < CH; ++j) {
        const float2 uy = ring_uy[r][j][wv];
        const float4 k = *(const float4*)&ring_k[r][j][lane * 4];
        s.x = fmaf(uy.x, k.x, s.x);
        s.y = fmaf(uy.x, k.y, s.y);
        s.z = fmaf(uy.x, k.z, s.z);
        s.w = fmaf(uy.x, k.w, s.w);
        floatx4 sv;
        sv.x = s.x; sv.y = s.y; sv.z = s.z; sv.w = s.w;
        __builtin_nontemporal_store(
            sv, (floatx4*)&states[(((size_t)b * Tc + tb + j) * Dc + i) * Dc +
                                  lane * 4]);
        if (lane == 0) yout[((size_t)b * Tc + tb + j) * Dc + i] = uy.y;
      }
      __threadfence_block();
      __hip_atomic_store(&prog_b[wv], c + 1, __ATOMIC_RELEASE,
                         __HIP_MEMORY_SCOPE_WORKGROUP);
    }
  }
}

// ---------------------------------------------------------------------------
extern "C" void kernel_launch(void* const* d_in, const int* in_sizes, int n_in,
                              void* d_out, int out_size, void* d_ws,
                              size_t ws_size, hipStream_t stream) {
  const float* x = (const float*)d_in[0];
  const float* S0 = (const float*)d_in[1];
  const float* Wk = (const float*)d_in[2];
  const float* Wq = (const float*)d_in[3];
  const float* Wv = (const float*)d_in[4];
  const float* Wb = (const float*)d_in[5];
  const float* gamma = (const float*)d_in[6];
  const float* beta_ln = (const float*)d_in[7];
  const float* Wsc = (const float*)d_in[8];
  const float* bsc = (const float*)d_in[9];

  float* out = (float*)d_out;
  float* yout = out;                              // [B,T,D]
  float* states = out + (size_t)Bc * Tc * Dc;     // [B,T,D,D]

  const size_t BTD = (size_t)Bc * Tc * Dc;
  float* ws = (float*)d_ws;
  float* K = ws;
  float* Q = K + BTD;
  float* V = Q + BTD;
  float* ysc = V + BTD;
  float* beta = ysc + BTD;
  float* kq = beta + (size_t)Bc * Tc;

  proj_kernel<<<(Bc * Tc) / RPB, 256, 0, stream>>>(
      x, Wk, Wq, Wv, Wb, gamma, beta_ln, Wsc, bsc, K, Q, V, ysc, beta, kq);
  scan_kernel<<<(Bc * Dc) / 4, 512, 0, stream>>>(S0, K, Q, V, ysc, beta, kq,
                                                 yout, states);
}

// Round 12
// 153.836 us; speedup vs baseline: 1.5810x; 1.0124x over previous
//
#include <hip/hip_runtime.h>
#include <math.h>

#define Bc 4
#define Tc 512
#define Fc 512
#define Dc 256
#define RPB 8   // rows per block (proj2 / LN granularity)
#define PF 4    // A-wave k/q prefetch depth
#define CH 16   // ring chunk (timesteps)
#define RS 4    // ring slots (chunks)
#define NC (Tc / CH)

typedef float floatx4 __attribute__((ext_vector_type(4)));

__device__ __forceinline__ float wred(float v) {
#pragma unroll
  for (int off = 32; off; off >>= 1) v += __shfl_xor(v, off, 64);
  return v;
}

__device__ __forceinline__ float rl(float v, int l) {
  return __int_as_float(__builtin_amdgcn_readlane(__float_as_int(v), l));
}

// Dual wave64 sum-reduce via DPP (row_shr 1/2/4/8 + row_bcast 15/31).
__device__ __forceinline__ void wred2_dpp(float& a, float& c) {
#define DPP_STEP(ctrl, rmask)                                                 \
  {                                                                           \
    float ta = __int_as_float(__builtin_amdgcn_update_dpp(                    \
        0, __float_as_int(a), (ctrl), (rmask), 0xf, true));                   \
    float tc = __int_as_float(__builtin_amdgcn_update_dpp(                    \
        0, __float_as_int(c), (ctrl), (rmask), 0xf, true));                   \
    a += ta;                                                                  \
    c += tc;                                                                  \
  }
  DPP_STEP(0x111, 0xf)  // row_shr:1
  DPP_STEP(0x112, 0xf)  // row_shr:2
  DPP_STEP(0x114, 0xf)  // row_shr:4
  DPP_STEP(0x118, 0xf)  // row_shr:8
  DPP_STEP(0x142, 0xa)  // row_bcast:15 -> rows 1,3
  DPP_STEP(0x143, 0xc)  // row_bcast:31 -> rows 2,3
#undef DPP_STEP
  a = rl(a, 63);
  c = rl(c, 63);
}

// Shared LN helper: computes xn for rows [row0, row0+8) into xnL[8][Fc].
// Wave w handles rows 2w, 2w+1; lane owns 8 elems.
__device__ __forceinline__ void ln_rows(const float* __restrict__ x,
                                        const float* __restrict__ gamma,
                                        const float* __restrict__ beta_ln,
                                        int row0, int wave, int lane,
                                        float (*xnL)[Fc]) {
#pragma unroll
  for (int rr = 0; rr < 2; ++rr) {
    const int r = wave * 2 + rr;
    const float* xr = x + (size_t)(row0 + r) * Fc;
    float4 a = *(const float4*)&xr[lane * 8];
    float4 b = *(const float4*)&xr[lane * 8 + 4];
    float s8 = a.x + a.y + a.z + a.w + b.x + b.y + b.z + b.w;
    float mu = wred(s8) * (1.0f / Fc);
    float d0 = a.x - mu, d1 = a.y - mu, d2 = a.z - mu, d3 = a.w - mu;
    float d4 = b.x - mu, d5 = b.y - mu, d6 = b.z - mu, d7 = b.w - mu;
    float sq = d0 * d0 + d1 * d1 + d2 * d2 + d3 * d3 + d4 * d4 + d5 * d5 +
               d6 * d6 + d7 * d7;
    float var = wred(sq) * (1.0f / Fc);
    float rs = rsqrtf(var + 1e-5f);
    float4 g0 = *(const float4*)&gamma[lane * 8];
    float4 g1 = *(const float4*)&gamma[lane * 8 + 4];
    float4 bl0 = *(const float4*)&beta_ln[lane * 8];
    float4 bl1 = *(const float4*)&beta_ln[lane * 8 + 4];
    float4 o0 = make_float4(d0 * rs * g0.x + bl0.x, d1 * rs * g0.y + bl0.y,
                            d2 * rs * g0.z + bl0.z, d3 * rs * g0.w + bl0.w);
    float4 o1 = make_float4(d4 * rs * g1.x + bl1.x, d5 * rs * g1.y + bl1.y,
                            d6 * rs * g1.z + bl1.z, d7 * rs * g1.w + bl1.w);
    *(float4*)&xnL[r][lane * 8] = o0;
    *(float4*)&xnL[r][lane * 8 + 4] = o1;
  }
}

// ---------------------------------------------------------------------------
// Kernel 1a (proj1): GEMM part, split-D. 512 blocks (2/CU -> 2 waves/SIMD),
// each 8 rows x 128 cols. Per-block weight slice 1 MB (total L2 traffic
// unchanged vs R6, but TLP doubled so FMA/LDS/load latencies interleave).
// Writes relu(K), relu(Q) RAW (unnormalized), V, ysc. half = bid&1 = xcd&1
// so each XCD touches one 128-col weight slice (1 MB, L2-resident).
// ---------------------------------------------------------------------------
__global__ __launch_bounds__(256, 2) void proj1_kernel(
    const float* __restrict__ x, const float* __restrict__ Wk,
    const float* __restrict__ Wq, const float* __restrict__ Wv,
    const float* __restrict__ gamma, const float* __restrict__ beta_ln,
    const float* __restrict__ Wsc, const float* __restrict__ bsc,
    float* __restrict__ Ko, float* __restrict__ Qo, float* __restrict__ Vo,
    float* __restrict__ ysco) {
  __shared__ __align__(16) float xn[RPB][Fc];  // 16 KB

  const int tid = threadIdx.x;
  const int wave = tid >> 6, lane = tid & 63;
  const int bid = blockIdx.x;          // 0..511
  const int half = bid & 1;            // col half (== xcd parity)
  const int row0 = (bid >> 1) * RPB;   // 8-row tile
  const int col = half * 128 + (tid & 127);
  const int rg = tid >> 7;             // 0/1 -> rows rg*4 .. rg*4+3

  ln_rows(x, gamma, beta_ln, row0, wave, lane, xn);
  __syncthreads();

  float accK[4], accQ[4], accV[4], accS[4];
#pragma unroll
  for (int r = 0; r < 4; ++r) accK[r] = accQ[r] = accV[r] = accS[r] = 0.0f;

  for (int f = 0; f < Fc; f += 4) {
    float wk[4], wq[4], wv[4], ws[4];
#pragma unroll
    for (int ff = 0; ff < 4; ++ff) {
      wk[ff] = Wk[(size_t)(f + ff) * Dc + col];
      wq[ff] = Wq[(size_t)(f + ff) * Dc + col];
      wv[ff] = Wv[(size_t)(f + ff) * Dc + col];
      ws[ff] = Wsc[(size_t)(f + ff) * Dc + col];
    }
#pragma unroll
    for (int r = 0; r < 4; ++r) {
      float4 xr = *(const float4*)&xn[rg * 4 + r][f];
      accK[r] = fmaf(xr.w, wk[3], fmaf(xr.z, wk[2], fmaf(xr.y, wk[1], fmaf(xr.x, wk[0], accK[r]))));
      accQ[r] = fmaf(xr.w, wq[3], fmaf(xr.z, wq[2], fmaf(xr.y, wq[1], fmaf(xr.x, wq[0], accQ[r]))));
      accV[r] = fmaf(xr.w, wv[3], fmaf(xr.z, wv[2], fmaf(xr.y, wv[1], fmaf(xr.x, wv[0], accV[r]))));
      accS[r] = fmaf(xr.w, ws[3], fmaf(xr.z, ws[2], fmaf(xr.y, ws[1], fmaf(xr.x, ws[0], accS[r]))));
    }
  }

  const float bs = bsc[col];
#pragma unroll
  for (int r = 0; r < 4; ++r) {
    const size_t row = (size_t)(row0 + rg * 4 + r);
    Ko[row * Dc + col] = fmaxf(accK[r], 0.0f);   // relu'd, unnormalized
    Qo[row * Dc + col] = fmaxf(accQ[r], 0.0f);
    Vo[row * Dc + col] = accV[r];
    ysco[row * Dc + col] = accS[r] + bs;
  }
}

// ---------------------------------------------------------------------------
// Kernel 1b (proj2): row-wide reductions + in-place normalization.
// 256 blocks x 8 rows. Recomputes LN (cheap) for the beta projection,
// reduces sumK/sumQ/kq/beta with the proven red/fin pattern, then
// normalizes K,Q in place (each element read+written by the same thread;
// in-block ordering via __syncthreads; rows are block-exclusive).
// ---------------------------------------------------------------------------
__global__ __launch_bounds__(256) void proj2_kernel(
    const float* __restrict__ x, const float* __restrict__ Wb,
    const float* __restrict__ gamma, const float* __restrict__ beta_ln,
    float* __restrict__ Ko, float* __restrict__ Qo, float* __restrict__ betao,
    float* __restrict__ kqo) {
  __shared__ __align__(16) float xn[RPB][Fc];
  __shared__ float red[4][32];
  __shared__ float fin[32];

  const int tid = threadIdx.x;
  const int wave = tid >> 6, lane = tid & 63;
  const int row0 = blockIdx.x * RPB;

  ln_rows(x, gamma, beta_ln, row0, wave, lane, xn);
  __syncthreads();

  const int d = tid;
  float pk[RPB], pq[RPB];
#pragma unroll
  for (int r = 0; r < RPB; ++r) {
    pk[r] = Ko[(size_t)(row0 + r) * Dc + d];  // already relu'd
    pq[r] = Qo[(size_t)(row0 + r) * Dc + d];
  }
#pragma unroll
  for (int r = 0; r < RPB; ++r) {
    float p0 = wred(pk[r]);
    float p1 = wred(pq[r]);
    float p2 = wred(pk[r] * pq[r]);
    float pb = xn[r][tid] * Wb[tid] + xn[r][tid + 256] * Wb[tid + 256];
    float p3 = wred(pb);
    if (lane == 0) {
      red[wave][r * 4 + 0] = p0;
      red[wave][r * 4 + 1] = p1;
      red[wave][r * 4 + 2] = p2;
      red[wave][r * 4 + 3] = p3;
    }
  }
  __syncthreads();
  if (tid < 32) fin[tid] = red[0][tid] + red[1][tid] + red[2][tid] + red[3][tid];
  __syncthreads();

#pragma unroll
  for (int r = 0; r < RPB; ++r) {
    const size_t row = (size_t)(row0 + r);
    float invK = 1.0f / (1e-5f + fin[r * 4 + 0]);
    float invQ = 1.0f / (1e-5f + fin[r * 4 + 1]);
    Ko[row * Dc + d] = pk[r] * invK;
    Qo[row * Dc + d] = pq[r] * invQ;
  }
  if (tid < RPB) {
    const size_t row = (size_t)(row0 + tid);
    float invK = 1.0f / (1e-5f + fin[tid * 4 + 0]);
    float invQ = 1.0f / (1e-5f + fin[tid * 4 + 1]);
    betao[row] = 1.0f / (1.0f + expf(-fin[tid * 4 + 3]));
    kqo[row] = fin[tid * 4 + 2] * invK * invQ;
  }
}

// ---------------------------------------------------------------------------
// Kernel 2: producer/consumer scan (exact R11 version — untouched).
// ---------------------------------------------------------------------------
__global__ __launch_bounds__(512) void scan_kernel(
    const float* __restrict__ S0, const float* __restrict__ K,
    const float* __restrict__ Q, const float* __restrict__ V,
    const float* __restrict__ ysc, const float* __restrict__ beta,
    const float* __restrict__ kq, float* __restrict__ yout,
    float* __restrict__ states) {
  __shared__ __align__(16) float ring_k[RS][CH][Dc];  // 64 KB
  __shared__ float2 ring_uy[RS][CH][4];               // 2 KB
  __shared__ int prog_a[4];
  __shared__ int prog_b[4];

  const int tid = threadIdx.x;
  const int wave = tid >> 6, lane = tid & 63;
  const int bid = blockIdx.x;               // 0..255
  const int xcd = bid & 7;                  // round-robin XCD id
  const int slot = bid >> 3;                // 0..31
  const int b = xcd >> 1;                   // 2 XCDs per batch
  const int sub = ((xcd & 1) << 5) | slot;  // 0..63 within batch
  const int i0 = sub * 4;                   // block rows: i0..i0+3

  if (tid < 4) {
    prog_a[tid] = 0;
    prog_b[tid] = 0;
  }
  __syncthreads();

  if (wave < 4) {
    // ======================= A: recurrence producer ========================
    const int i = i0 + wave;
    float4 s = *(const float4*)&S0[((size_t)(b * Dc + i)) * Dc + lane * 4];

    const float* Kb = K + (size_t)b * Tc * Dc;
    const float* Qb = Q + (size_t)b * Tc * Dc;
    const float* Vb = V + (size_t)b * Tc * Dc;
    const float* Yb = ysc + (size_t)b * Tc * Dc;
    const float* bb_p = beta + (size_t)b * Tc;
    const float* kq_p = kq + (size_t)b * Tc;

    float4 kb[PF], qb[PF];
#pragma unroll
    for (int j = 0; j < PF; ++j) {
      kb[j] = *(const float4*)&Kb[(size_t)j * Dc + lane * 4];
      qb[j] = *(const float4*)&Qb[(size_t)j * Dc + lane * 4];
    }
    const int sl = lane & 15;
    float vcur = Vb[(size_t)sl * Dc + i];
    float ycur = Yb[(size_t)sl * Dc + i];
    float bcur = bb_p[sl];
    float kqcur = kq_p[sl];

    for (int c = 0; c < NC; ++c) {
      if (c >= RS) {
        const int need = c - RS + 1;
#pragma unroll
        for (int m = 0; m < 4; ++m) {
          while (__hip_atomic_load(&prog_b[m], __ATOMIC_ACQUIRE,
                                   __HIP_MEMORY_SCOPE_WORKGROUP) < need)
            __builtin_amdgcn_s_sleep(2);
        }
      }
      const int cn = (c + 1 < NC) ? c + 1 : c;
      const int tbn = cn * CH;
      float vnxt = Vb[(size_t)(tbn + sl) * Dc + i];
      float ynxt = Yb[(size_t)(tbn + sl) * Dc + i];
      float bnxt = bb_p[tbn + sl];
      float kqnxt = kq_p[tbn + sl];

      const int r = c & (RS - 1);
      const int tb = c * CH;
#pragma unroll
      for (int j = 0; j < CH; ++j) {
        const int t = tb + j;
        const float4 k = kb[j & (PF - 1)];
        const float4 q = qb[j & (PF - 1)];
        const float vv = rl(vcur, j);
        const float yb = rl(ycur, j);
        const float bbs = rl(bcur, j);
        const float kqv = rl(kqcur, j);

        const int tn = (t + PF < Tc) ? t + PF : Tc - 1;
        kb[j & (PF - 1)] = *(const float4*)&Kb[(size_t)tn * Dc + lane * 4];
        qb[j & (PF - 1)] = *(const float4*)&Qb[(size_t)tn * Dc + lane * 4];

        float a = (s.x * k.x + s.y * k.y) + (s.z * k.z + s.w * k.w);
        float c2 = (s.x * q.x + s.y * q.y) + (s.z * q.z + s.w * q.w);
        wred2_dpp(a, c2);

        const float wcoef = bbs * (vv - a);
        s.x = fmaf(wcoef, k.x, s.x);
        s.y = fmaf(wcoef, k.y, s.y);
        s.z = fmaf(wcoef, k.z, s.z);
        s.w = fmaf(wcoef, k.w, s.w);

        if (wave == (j & 3)) *(float4*)&ring_k[r][j][lane * 4] = k;
        if (lane == 0) {
          float2 uy;
          uy.x = wcoef;
          uy.y = c2 + wcoef * kqv + yb;
          ring_uy[r][j][wave] = uy;
        }
      }
      __threadfence_block();
      __hip_atomic_store(&prog_a[wave], c + 1, __ATOMIC_RELEASE,
                         __HIP_MEMORY_SCOPE_WORKGROUP);
      vcur = vnxt;
      ycur = ynxt;
      bcur = bnxt;
      kqcur = kqnxt;
    }
  } else {
    // ======================= B: states store stream ========================
    const int wv = wave - 4;
    const int i = i0 + wv;
    float4 s = *(const float4*)&S0[((size_t)(b * Dc + i)) * Dc + lane * 4];

    for (int c = 0; c < NC; ++c) {
      const int need = c + 1;
#pragma unroll
      for (int m = 0; m < 4; ++m) {
        while (__hip_atomic_load(&prog_a[m], __ATOMIC_ACQUIRE,
                                 __HIP_MEMORY_SCOPE_WORKGROUP) < need)
          __builtin_amdgcn_s_sleep(2);
      }

      const int r = c & (RS - 1);
      const int tb = c * CH;
#pragma unroll
      for (int j = 0; j < CH; ++j) {
        const float2 uy = ring_uy[r][j][wv];
        const float4 k = *(const float4*)&ring_k[r][j][lane * 4];
        s.x = fmaf(uy.x, k.x, s.x);
        s.y = fmaf(uy.x, k.y, s.y);
        s.z = fmaf(uy.x, k.z, s.z);
        s.w = fmaf(uy.x, k.w, s.w);
        floatx4 sv;
        sv.x = s.x; sv.y = s.y; sv.z = s.z; sv.w = s.w;
        __builtin_nontemporal_store(
            sv, (floatx4*)&states[(((size_t)b * Tc + tb + j) * Dc + i) * Dc +
                                  lane * 4]);
        if (lane == 0) yout[((size_t)b * Tc + tb + j) * Dc + i] = uy.y;
      }
      __threadfence_block();
      __hip_atomic_store(&prog_b[wv], c + 1, __ATOMIC_RELEASE,
                         __HIP_MEMORY_SCOPE_WORKGROUP);
    }
  }
}

// ---------------------------------------------------------------------------
extern "C" void kernel_launch(void* const* d_in, const int* in_sizes, int n_in,
                              void* d_out, int out_size, void* d_ws,
                              size_t ws_size, hipStream_t stream) {
  const float* x = (const float*)d_in[0];
  const float* S0 = (const float*)d_in[1];
  const float* Wk = (const float*)d_in[2];
  const float* Wq = (const float*)d_in[3];
  const float* Wv = (const float*)d_in[4];
  const float* Wb = (const float*)d_in[5];
  const float* gamma = (const float*)d_in[6];
  const float* beta_ln = (const float*)d_in[7];
  const float* Wsc = (const float*)d_in[8];
  const float* bsc = (const float*)d_in[9];

  float* out = (float*)d_out;
  float* yout = out;                              // [B,T,D]
  float* states = out + (size_t)Bc * Tc * Dc;     // [B,T,D,D]

  const size_t BTD = (size_t)Bc * Tc * Dc;
  float* ws = (float*)d_ws;
  float* K = ws;
  float* Q = K + BTD;
  float* V = Q + BTD;
  float* ysc = V + BTD;
  float* beta = ysc + BTD;
  float* kq = beta + (size_t)Bc * Tc;

  proj1_kernel<<<(Bc * Tc) / RPB * 2, 256, 0, stream>>>(
      x, Wk, Wq, Wv, gamma, beta_ln, Wsc, bsc, K, Q, V, ysc);
  proj2_kernel<<<(Bc * Tc) / RPB, 256, 0, stream>>>(x, Wb, gamma, beta_ln, K,
                                                    Q, beta, kq);
  scan_kernel<<<(Bc * Dc) / 4, 512, 0, stream>>>(S0, K, Q, V, ysc, beta, kq,
                                                 yout, states);
}